// Round 10
// baseline (70.350 us; speedup 1.0000x reference)
//
#include <hip/hip_runtime.h>

#define S_LEN 1024
#define D_DIM 64
#define NPOS 64
#define NBLOCKS 3072   // 12288 waves -> 4 rows/wave at 49152 rows

typedef float floatx4 __attribute__((ext_vector_type(4)));

__device__ __forceinline__ float sigmoid_fast(float x) {
    return __builtin_amdgcn_rcpf(1.0f + __expf(-x));
}

// f32 -> bf16 bits, round-to-nearest-even
__device__ __forceinline__ unsigned bf16_bits(float x) {
    unsigned u = __float_as_uint(x);
    return (u + 0x7fffu + ((u >> 16) & 1u)) >> 16;
}

__device__ __forceinline__ void load_row4(const float* __restrict__ arow, int lane, float4* xv) {
    #pragma unroll
    for (int k = 0; k < 4; ++k)
        xv[k] = *reinterpret_cast<const float4*>(arow + k * 256 + 4 * lane);
}

__global__ __launch_bounds__(256) void cope_kernel(
    const float* __restrict__ attn,
    const float* __restrict__ query,
    const float* __restrict__ pe,     // [D_DIM][NPOS]
    float* __restrict__ out,
    int nrows)
{
    const int lane   = threadIdx.x & 63;
    const int gwave  = blockIdx.x * 4 + (threadIdx.x >> 6);
    const int nwaves = NBLOCKS * 4;

    int row = gwave;
    float4 xv[4];
    if (row < nrows)
        load_row4(attn + (size_t)__builtin_amdgcn_readfirstlane(row) * S_LEN, lane, xv);

    for (; row < nrows; row += nwaves) {
        const int urow = __builtin_amdgcn_readfirstlane(row);
        const int nrow = row + nwaves;

        // prefetch next row's attn: keeps 4KB/wave of reads in flight across
        // the whole compute phase (no launch_bounds clamp -> no spill)
        float4 nx[4];
        if (nrow < nrows)
            load_row4(attn + (size_t)__builtin_amdgcn_readfirstlane(nrow) * S_LEN, lane, nx);

        // GEMV: logits[lane] = sum_d q[d]*pe[d][lane]; q uniform (s_loads),
        // pe (16KB) L1-resident; 4 accumulators break the FMA chain.
        const float* qrow = query + (size_t)urow * D_DIM;
        float a0 = 0.f, a1 = 0.f, a2 = 0.f, a3 = 0.f;
        #pragma unroll
        for (int d = 0; d < D_DIM; d += 4) {
            a0 = fmaf(qrow[d + 0], pe[(d + 0) * NPOS + lane], a0);
            a1 = fmaf(qrow[d + 1], pe[(d + 1) * NPOS + lane], a1);
            a2 = fmaf(qrow[d + 2], pe[(d + 2) * NPOS + lane], a2);
            a3 = fmaf(qrow[d + 3], pe[(d + 3) * NPOS + lane], a3);
        }
        const float lreg = (a0 + a1) + (a2 + a3);

        // pack (logits[lane], logits[lane+1]) as bf16 pair in one u32
        float nb = __shfl_down(lreg, 1, 64);      // lane 63: undefined but w==0 there
        const int packed = (int)(bf16_bits(lreg) | (bf16_bits(nb) << 16));

        // sigmoid + per-lane section sums (section k = elements [256k, 256k+256))
        float s[4], I[4];
        #pragma unroll
        for (int k = 0; k < 4; ++k) {
            xv[k].x = sigmoid_fast(xv[k].x);
            xv[k].y = sigmoid_fast(xv[k].y);
            xv[k].z = sigmoid_fast(xv[k].z);
            xv[k].w = sigmoid_fast(xv[k].w);
            s[k] = (xv[k].x + xv[k].y) + (xv[k].z + xv[k].w);
        }

        // 4 independent in-wave inclusive SUFFIX scans (Kogge-Stone, 6 steps)
        #pragma unroll
        for (int k = 0; k < 4; ++k) {
            float v = s[k];
            #pragma unroll
            for (int off = 1; off < 64; off <<= 1) {
                float o = __shfl_down(v, off, 64);
                if (lane + off < 64) v += o;
            }
            I[k] = v;
        }

        // section totals -> tails (sum of gates in later sections)
        float T1 = __shfl(I[1], 0, 64);
        float T2 = __shfl(I[2], 0, 64);
        float T3 = __shfl(I[3], 0, 64);
        float tail[4] = { T1 + T2 + T3, T2 + T3, T3, 0.f };

        float* orow = out + (size_t)urow * S_LEN;
        #pragma unroll
        for (int k = 0; k < 4; ++k) {
            float after = (I[k] - s[k]) + tail[k];   // gates strictly after this lane's chunk
            float p3 = xv[k].w + after;
            float p2 = xv[k].z + p3;
            float p1 = xv[k].y + p2;
            float p0 = xv[k].x + p1;
            float pv[4] = { p0, p1, p2, p3 };
            float o4[4];
            #pragma unroll
            for (int i = 0; i < 4; ++i) {
                float pc = fminf(pv[i], 63.0f);
                int   fi = (int)pc;                 // pc >= 0: trunc == floor
                float w  = pc - (float)fi;
                int  wrd = __shfl(packed, fi, 64);  // one bpermute per element
                float lf = __uint_as_float((unsigned)wrd << 16);         // logits[fi]
                float lc = __uint_as_float((unsigned)wrd & 0xffff0000u); // logits[fi+1]
                o4[i] = lc * w + lf * (1.0f - w);
            }
            floatx4 ov = { o4[0], o4[1], o4[2], o4[3] };
            // nt store: no L2 write-allocate; out is never re-read (round-9 win)
            __builtin_nontemporal_store(ov, reinterpret_cast<floatx4*>(orow + k * 256 + 4 * lane));
        }

        #pragma unroll
        for (int k = 0; k < 4; ++k) xv[k] = nx[k];
    }
}

extern "C" void kernel_launch(void* const* d_in, const int* in_sizes, int n_in,
                              void* d_out, int out_size, void* d_ws, size_t ws_size,
                              hipStream_t stream) {
    const float* attn  = (const float*)d_in[0];   // [B,H,S,S] f32
    const float* query = (const float*)d_in[1];   // [B,H,S,D] f32
    const float* pe    = (const float*)d_in[2];   // [1,D,NPOS] f32
    float* out = (float*)d_out;                   // [B,H,S,S] f32

    const int rows = in_sizes[0] / S_LEN;         // B*H*S = 49152
    cope_kernel<<<NBLOCKS, 256, 0, stream>>>(attn, query, pe, out, rows);
}

// Round 11
// 65.249 us; speedup vs baseline: 1.0782x; 1.0782x over previous
//
#include <hip/hip_runtime.h>

#define S_LEN 1024
#define D_DIM 64
#define NPOS 64

typedef float floatx4 __attribute__((ext_vector_type(4)));

__device__ __forceinline__ float sigmoid_fast(float x) {
    return __builtin_amdgcn_rcpf(1.0f + __expf(-x));
}

// f32 -> bf16 bits, round-to-nearest-even
__device__ __forceinline__ unsigned bf16_bits(float x) {
    unsigned u = __float_as_uint(x);
    return (u + 0x7fffu + ((u >> 16) & 1u)) >> 16;
}

__global__ __launch_bounds__(256) void cope_kernel(
    const float* __restrict__ attn,
    const float* __restrict__ query,
    const float* __restrict__ pe,     // [D_DIM][NPOS]
    float* __restrict__ out,
    int nrows)
{
    const int lane = threadIdx.x & 63;
    const int row  = blockIdx.x * 4 + (threadIdx.x >> 6);   // one row per wave
    if (row >= nrows) return;
    const int urow = __builtin_amdgcn_readfirstlane(row);

    // issue the 4 coalesced 1KB loads immediately at wave launch;
    // block turnover supplies cross-row memory-level parallelism
    const float* arow = attn + (size_t)urow * S_LEN;
    float4 xv[4];
    #pragma unroll
    for (int k = 0; k < 4; ++k)
        xv[k] = *reinterpret_cast<const float4*>(arow + k * 256 + 4 * lane);

    // GEMV while attn loads are in flight: logits[lane] = sum_d q[d]*pe[d][lane]
    // q via uniform s_loads; pe (16KB) L1-resident; 4 accs break the FMA chain.
    const float* qrow = query + (size_t)urow * D_DIM;
    float a0 = 0.f, a1 = 0.f, a2 = 0.f, a3 = 0.f;
    #pragma unroll
    for (int d = 0; d < D_DIM; d += 4) {
        a0 = fmaf(qrow[d + 0], pe[(d + 0) * NPOS + lane], a0);
        a1 = fmaf(qrow[d + 1], pe[(d + 1) * NPOS + lane], a1);
        a2 = fmaf(qrow[d + 2], pe[(d + 2) * NPOS + lane], a2);
        a3 = fmaf(qrow[d + 3], pe[(d + 3) * NPOS + lane], a3);
    }
    const float lreg = (a0 + a1) + (a2 + a3);

    // pack (logits[lane], logits[lane+1]) as bf16 pair in one u32
    float nb = __shfl_down(lreg, 1, 64);      // lane 63: undefined but w==0 there
    const int packed = (int)(bf16_bits(lreg) | (bf16_bits(nb) << 16));

    // sigmoid + per-lane section sums (section k = elements [256k, 256k+256))
    float s[4], I[4];
    #pragma unroll
    for (int k = 0; k < 4; ++k) {
        xv[k].x = sigmoid_fast(xv[k].x);
        xv[k].y = sigmoid_fast(xv[k].y);
        xv[k].z = sigmoid_fast(xv[k].z);
        xv[k].w = sigmoid_fast(xv[k].w);
        s[k] = (xv[k].x + xv[k].y) + (xv[k].z + xv[k].w);
    }

    // 4 independent in-wave inclusive SUFFIX scans (Kogge-Stone, 6 steps)
    #pragma unroll
    for (int k = 0; k < 4; ++k) {
        float v = s[k];
        #pragma unroll
        for (int off = 1; off < 64; off <<= 1) {
            float o = __shfl_down(v, off, 64);
            if (lane + off < 64) v += o;
        }
        I[k] = v;
    }

    // section totals -> tails (sum of gates in later sections)
    float T1 = __shfl(I[1], 0, 64);
    float T2 = __shfl(I[2], 0, 64);
    float T3 = __shfl(I[3], 0, 64);
    float tail[4] = { T1 + T2 + T3, T2 + T3, T3, 0.f };

    float* orow = out + (size_t)urow * S_LEN;
    #pragma unroll
    for (int k = 0; k < 4; ++k) {
        float after = (I[k] - s[k]) + tail[k];   // gates strictly after this lane's chunk
        float p3 = xv[k].w + after;
        float p2 = xv[k].z + p3;
        float p1 = xv[k].y + p2;
        float p0 = xv[k].x + p1;
        float pv[4] = { p0, p1, p2, p3 };
        float o4[4];
        #pragma unroll
        for (int i = 0; i < 4; ++i) {
            float pc = fminf(pv[i], 63.0f);
            int   fi = (int)pc;                 // pc >= 0: trunc == floor
            float w  = pc - (float)fi;
            int  wrd = __shfl(packed, fi, 64);  // one bpermute per element
            float lf = __uint_as_float((unsigned)wrd << 16);         // logits[fi]
            float lc = __uint_as_float((unsigned)wrd & 0xffff0000u); // logits[fi+1]
            o4[i] = lc * w + lf * (1.0f - w);
        }
        floatx4 ov = { o4[0], o4[1], o4[2], o4[3] };
        // nt store: no L2 write-allocate; out is never re-read (round-9 win)
        __builtin_nontemporal_store(ov, reinterpret_cast<floatx4*>(orow + k * 256 + 4 * lane));
    }
}

extern "C" void kernel_launch(void* const* d_in, const int* in_sizes, int n_in,
                              void* d_out, int out_size, void* d_ws, size_t ws_size,
                              hipStream_t stream) {
    const float* attn  = (const float*)d_in[0];   // [B,H,S,S] f32
    const float* query = (const float*)d_in[1];   // [B,H,S,D] f32
    const float* pe    = (const float*)d_in[2];   // [1,D,NPOS] f32
    float* out = (float*)d_out;                   // [B,H,S,S] f32

    const int rows   = in_sizes[0] / S_LEN;       // B*H*S = 49152
    const int blocks = (rows + 3) / 4;            // one row per wave, 4 waves/block
    cope_kernel<<<blocks, 256, 0, stream>>>(attn, query, pe, out, rows);
}